// Round 7
// baseline (13391.382 us; speedup 1.0000x reference)
//
#include <hip/hip_runtime.h>
#include <stdint.h>

#define BDIM 64
#define TDIM 512
#define EDIM 512
#define HDIM 512

typedef __attribute__((ext_vector_type(8))) short bf16x8;
typedef __attribute__((ext_vector_type(4))) float f32x4;
typedef __attribute__((ext_vector_type(4))) unsigned int u32x4;
typedef __attribute__((ext_vector_type(4))) unsigned short u16x4;
typedef unsigned long long u64t;

static __device__ __forceinline__ unsigned short f2bf(float f) {
  union { float f; uint32_t u; } c; c.f = f;
  uint32_t u = c.u;
  uint32_t r = u + 0x7fffu + ((u >> 16) & 1u);
  return (unsigned short)(r >> 16);
}
static __device__ __forceinline__ float bf2f(unsigned short s) {
  union { uint32_t u; float f; } c; c.u = ((uint32_t)s) << 16;
  return c.f;
}

static __device__ __forceinline__ unsigned char f2e4m3(float f) {
  uint32_t u = __float_as_uint(f);
  unsigned char s = (unsigned char)((u >> 31) << 7);
  float a = fabsf(f);
  if (a >= 448.f) return (unsigned char)(s | 0x7e);
  if (a < 0.015625f) {
    int q = (int)rintf(a * 512.f);
    if (q >= 8) return (unsigned char)(s | 0x08);
    return (unsigned char)(s | q);
  }
  int e; frexpf(a, &e);
  int E = e - 1;
  int q = (int)rintf(ldexpf(a, 3 - E));
  if (q == 16) { q = 8; E++; }
  int exp8 = E + 7;
  if (exp8 >= 16) return (unsigned char)(s | 0x7e);
  return (unsigned char)(s | (exp8 << 3) | (q & 7));
}

#define SWZ2(row, b) (((row)*1024) + ((b) ^ ((((row)&15))<<4)))
#define SWZA(row, byteInRow) ((((row)*128) + (byteInRow)) ^ ((((row)&7))<<4))
#define LGRX(r) (((((r)&3))<<6) | ((((r)&12))<<2))
#define H8S 528

#define SBAR() { __builtin_amdgcn_s_barrier(); __builtin_amdgcn_sched_barrier(0); }
#define WAIT_LGKM0() { asm volatile("s_waitcnt lgkmcnt(0)" ::: "memory"); __builtin_amdgcn_sched_barrier(0); }
#define WAIT_VM0() { asm volatile("s_waitcnt vmcnt(0)" ::: "memory"); __builtin_amdgcn_sched_barrier(0); }

// ---------------- small utility kernels ----------------

__global__ void sentinel_kern(float* out, int n) {
  for (int i = blockIdx.x * blockDim.x + threadIdx.x; i < n; i += gridDim.x * blockDim.x)
    out[i] = -12345.0f;
}

__global__ void conv_w(const float* __restrict__ Wz, const float* __restrict__ Wr,
                       const float* __restrict__ Wh,
                       unsigned short* __restrict__ Wxb, unsigned short* __restrict__ Whb,
                       unsigned char* __restrict__ Wr8) {
  int idx = blockIdx.x * 256 + threadIdx.x;
  if (idx >= 3 * 512 * 1024) return;
  int g = idx >> 19;
  int rem = idx & 524287;
  int j = rem >> 10, k = rem & 1023;
  const float* W = (g == 0) ? Wz : (g == 1) ? Wr : Wh;
  float v = W[(size_t)j * 1024 + k];
  unsigned short b = f2bf(v);
  if (k < 512) Wxb[((size_t)g * 512 + j) * 512 + k] = b;
  else {
    Whb[((size_t)g * 512 + j) * 512 + (k - 512)] = b;
    if (g == 1) Wr8[(size_t)j * 512 + (k - 512)] = f2e4m3(v * 16.f);
  }
}

__global__ void conv_x(const float* __restrict__ x, unsigned short* __restrict__ xb, int n4) {
  for (int i = blockIdx.x * blockDim.x + threadIdx.x; i < n4; i += gridDim.x * blockDim.x) {
    f32x4 v = ((const f32x4*)x)[i];
    u16x4 o;
    o[0] = f2bf(v[0]); o[1] = f2bf(v[1]); o[2] = f2bf(v[2]); o[3] = f2bf(v[3]);
    ((u16x4*)xb)[i] = o;
  }
}

__global__ void add_out(float* __restrict__ out, const float* __restrict__ Hb, int n4) {
  for (int i = blockIdx.x * blockDim.x + threadIdx.x; i < n4; i += gridDim.x * blockDim.x) {
    f32x4 a = ((const f32x4*)out)[i];
    f32x4 b = ((const f32x4*)Hb)[i];
    ((f32x4*)out)[i] = a + b;
  }
}

// ---------------- phase A: G = x @ Wx^T + bias (bf16 out) ----------------

__global__ __launch_bounds__(256, 2)
void gru_xproj(const unsigned short* __restrict__ xb,
               const unsigned short* __restrict__ Wxb,
               const float* __restrict__ bz, const float* __restrict__ br,
               const float* __restrict__ bh,
               unsigned short* __restrict__ Gb) {
  __shared__ __align__(16) unsigned short lA[128 * 64];
  __shared__ __align__(16) unsigned short lB[128 * 64];
  const int tid = threadIdx.x;
  const int m0 = blockIdx.x * 128;
  const int n0 = blockIdx.y * 128;
  const int w = tid >> 6, lane = tid & 63, cl = lane & 15, q = lane >> 4;
  const int wr = w >> 1, wc = w & 1;
  f32x4 acc[4][4];
#pragma unroll
  for (int i = 0; i < 4; i++)
#pragma unroll
    for (int j = 0; j < 4; j++) acc[i][j] = (f32x4){0.f, 0.f, 0.f, 0.f};

  for (int ko = 0; ko < 8; ko++) {
    int k0 = ko * 64;
#pragma unroll
    for (int cc = 0; cc < 4; cc++) {
      int qq = tid * 4 + cc;
      int row = qq >> 3, kc = qq & 7;
      u32x4 va = *(const u32x4*)(xb + ((size_t)(m0 + row) * EDIM + k0 + kc * 8));
      *(u32x4*)((char*)lA + SWZA(row, kc * 16)) = va;
      u32x4 vb = *(const u32x4*)(Wxb + ((size_t)(n0 + row) * EDIM + k0 + kc * 8));
      *(u32x4*)((char*)lB + SWZA(row, kc * 16)) = vb;
    }
    __syncthreads();
#pragma unroll
    for (int ks = 0; ks < 2; ks++) {
      bf16x8 af[4], bfv[4];
#pragma unroll
      for (int i = 0; i < 4; i++) {
        int rl = wr * 64 + i * 16 + cl;
        af[i] = *(const bf16x8*)((char*)lA + SWZA(rl, ks * 64 + q * 16));
      }
#pragma unroll
      for (int j = 0; j < 4; j++) {
        int rl = wc * 64 + j * 16 + cl;
        bfv[j] = *(const bf16x8*)((char*)lB + SWZA(rl, ks * 64 + q * 16));
      }
#pragma unroll
      for (int i = 0; i < 4; i++)
#pragma unroll
        for (int j = 0; j < 4; j++)
          acc[i][j] = __builtin_amdgcn_mfma_f32_16x16x32_bf16(af[i], bfv[j], acc[i][j], 0, 0, 0);
    }
    __syncthreads();
  }
  const int g = n0 >> 9;
  const float* bias = (g == 0) ? bz : (g == 1) ? br : bh;
#pragma unroll
  for (int i = 0; i < 4; i++) {
#pragma unroll
    for (int j = 0; j < 4; j++) {
      int n = n0 + wc * 64 + j * 16 + cl;
      float bv = bias[n & 511];
#pragma unroll
      for (int ii = 0; ii < 4; ii++) {
        int m = m0 + wr * 64 + i * 16 + q * 4 + ii;
        Gb[(size_t)m * 1536 + n] = f2bf(acc[i][j][ii] + bv);
      }
    }
  }
}

// ---------------- persistent recurrence — ABLATION TEMPLATE ----------------
// MODE 0: full algorithm (correct). MODE 1: poll deleted (chain cost only).
// MODE 2: sync skeleton only (poll + barrier + flag; no data path).
// One-time setup kept in ALL modes so LDS/occupancy footprint is identical.

template<int MODE>
__global__ __launch_bounds__(256, 1)
void gru_persist(const unsigned short* __restrict__ Gb,
                 const float* __restrict__ h0,
                 unsigned short* __restrict__ Hstb,
                 unsigned int*   __restrict__ flags,
                 float* __restrict__ outp,
                 float* __restrict__ Hb,
                 const unsigned short* __restrict__ Whb,
                 const unsigned char*  __restrict__ Wr8) {
  __shared__ __align__(16) unsigned short lw_z[32 * 512];
  __shared__ __align__(16) unsigned short lw_h[32 * 512];
  __shared__ __align__(16) unsigned short lhb[16 * 512];
  __shared__ __align__(16) unsigned short lrh[16 * 512];
  __shared__ __align__(16) unsigned short lgr[16 * 512];
  __shared__ __align__(16) unsigned char  lh8[16 * H8S];
  __shared__ __align__(16) unsigned short lgz[16 * 36];
  __shared__ __align__(16) unsigned short lgh[16 * 36];
  __shared__ float lz[16 * 32];

  const int tid = threadIdx.x;
  const int bid = blockIdx.x;
  const int gid = bid & 7;
  const int cg = bid >> 3;
  const int dir = gid >> 2;
  const int bg = gid & 3;
  const int j0 = cg * 32;
  const int w = tid >> 6;
  const int lane = tid & 63;
  const int c = lane & 15;
  const int q = lane >> 4;
  const int rj0 = w * 128;
  const int HHALF = 2 * 64 * 512;
  unsigned int* fown  = flags + (gid * 16 + cg) * 32;
  unsigned int* fpoll = flags + (gid * 16 + (lane & 15)) * 32;

  // ---- one-time setup (ALL modes: keeps LDS/VGPR footprint comparable) ----
  {
    int col = tid >> 3, ch = tid & 7;
#pragma unroll
    for (int u = 0; u < 8; u++) {
      u32x4 vz = *(const u32x4*)(Whb + (((size_t)0 * 512 + j0 + col) * 512) + ch * 64 + u * 8);
      *(u32x4*)((char*)lw_z + SWZ2(col, ch * 128 + u * 16)) = vz;
      u32x4 vh = *(const u32x4*)(Whb + (((size_t)2 * 512 + j0 + col) * 512) + ch * 64 + u * 8);
      *(u32x4*)((char*)lw_h + SWZ2(col, ch * 128 + u * 16)) = vh;
    }
  }
  u64t wrg[8][16];
  {
    const u64t* wsrc = (const u64t*)Wr8;
#pragma unroll
    for (int ct = 0; ct < 8; ct++)
#pragma unroll
      for (int ks = 0; ks < 16; ks++)
        wrg[ct][ks] = wsrc[(size_t)(rj0 + ct * 16 + c) * 64 + ks * 4 + q];
  }
  float hp[4];
  const int hsub = w - 2;
#pragma unroll
  for (int i = 0; i < 4; i++) hp[i] = 0.f;
  if (w >= 2) {
#pragma unroll
    for (int i = 0; i < 4; i++)
      hp[i] = h0[(size_t)(bg * 16 + q * 4 + i) * HDIM + j0 + hsub * 16 + c];
  }
  {
    int row = tid >> 4, jl2 = (tid & 15) * 2;
    int b = bg * 16 + row;
    float v0 = h0[(size_t)b * HDIM + j0 + jl2];
    float v1 = h0[(size_t)b * HDIM + j0 + jl2 + 1];
    unsigned int pk = (unsigned int)f2bf(v0) | ((unsigned int)f2bf(v1) << 16);
    __hip_atomic_store((unsigned int*)&Hstb[(size_t)(dir * 64 + b) * 512 + j0 + jl2], pk,
                       __ATOMIC_RELAXED, __HIP_MEMORY_SCOPE_AGENT);
  }
  asm volatile("s_waitcnt vmcnt(0)" ::: "memory");
  __syncthreads();
  if (tid == 0)
    __hip_atomic_store(fown, 1u, __ATOMIC_RELAXED, __HIP_MEMORY_SCOPE_AGENT);

  const float inv256 = 1.f / 256.f;

  for (int s = 1; s <= TDIM; s++) {
    int t = dir ? (TDIM - s) : (s - 1);
    const unsigned short* Hstb_r = Hstb + (size_t)((s - 1) & 1) * HHALF;
    unsigned short* Hstb_w = Hstb + (size_t)(s & 1) * HHALF;

    unsigned int gzv = 0, ghv = 0;
    if constexpr (MODE != 2) {
      // pre-poll: current-step lgr DMA (waves 0,1)
      if (w < 2) {
#pragma unroll
        for (int k = 0; k < 8; k++) {
          int r = w * 8 + k;
          const unsigned short* src = Gb + ((size_t)(bg * 16 + r) * TDIM + t) * 1536 + 512
                                      + (((unsigned)(lane * 16) ^ LGRX(r)) >> 1);
          __builtin_amdgcn_global_load_lds((const unsigned int*)src,
              (unsigned int*)((char*)lgr + r * 1024), 16, 0, 0);
        }
      }
      int zr = tid >> 4, zl = (tid & 15) * 2;
      size_t mz = ((size_t)(bg * 16 + zr) * TDIM + t) * 1536;
      gzv = *(const unsigned int*)(Gb + mz + j0 + zl);
      ghv = *(const unsigned int*)(Gb + mz + 1024 + j0 + zl);
    }

    if constexpr (MODE != 1) {
      // flat rendezvous: wave 0, lanes 0-15 poll 16 distinct 128B lines
      if (w == 0) {
        unsigned tgt = (unsigned)s;
        while (true) {
          unsigned fv = tgt;
          if (lane < 16)
            fv = __hip_atomic_load(fpoll, __ATOMIC_RELAXED, __HIP_MEMORY_SCOPE_AGENT);
          if (__all(fv >= tgt)) break;
          __builtin_amdgcn_s_sleep(1);
        }
      }
    }
    SBAR();   // B1

    if constexpr (MODE != 2) {
      {
        int zr = tid >> 4, zl4 = (tid & 15) * 4;
        *(unsigned int*)((char*)lgz + zr * 72 + zl4) = gzv;
        *(unsigned int*)((char*)lgh + zr * 72 + zl4) = ghv;
      }
      {
        int row = tid >> 4, seg = tid & 15;
        const char* srcb = (const char*)Hstb_r + ((size_t)(dir * 64 + bg * 16 + row) * 512) * 2;
        u64t v[8];
#pragma unroll
        for (int i = 0; i < 8; i++)
          v[i] = __hip_atomic_load((const u64t*)(srcb + i * 128 + seg * 8),
                                   __ATOMIC_RELAXED, __HIP_MEMORY_SCOPE_AGENT);
        char* dst = (char*)lhb;
#pragma unroll
        for (int i = 0; i < 8; i++)
          *(u64t*)(dst + SWZ2(row, i * 128 + seg * 8)) = v[i];
#pragma unroll
        for (int i = 0; i < 8; i++) {
          const unsigned short* sp = (const unsigned short*)&v[i];
          float f0 = bf2f(sp[0]) * 16.f, f1 = bf2f(sp[1]) * 16.f;
          float f2 = bf2f(sp[2]) * 16.f, f3 = bf2f(sp[3]) * 16.f;
          int d = 0;
          d = __builtin_amdgcn_cvt_pk_fp8_f32(f0, f1, d, false);
          d = __builtin_amdgcn_cvt_pk_fp8_f32(f2, f3, d, true);
          *(unsigned int*)(lh8 + row * H8S + i * 64 + seg * 4) = (unsigned int)d;
        }
      }
      __syncthreads();   // B2: full drain (staging + DMA)

      u64t af8[16];
#pragma unroll
      for (int ks = 0; ks < 16; ks++)
        af8[ks] = *(const u64t*)(lh8 + c * H8S + ks * 32 + q * 8);

      f32x4 racc[8];
#pragma unroll
      for (int ct = 0; ct < 8; ct++) racc[ct] = (f32x4){0.f, 0.f, 0.f, 0.f};
#pragma unroll
      for (int ks = 0; ks < 16; ks++)
#pragma unroll
        for (int ct = 0; ct < 8; ct++)
          racc[ct] = __builtin_amdgcn_mfma_f32_16x16x32_fp8_fp8(
              (long)af8[ks], (long)wrg[ct][ks], racc[ct], 0, 0, 0);

      if (w < 2) {
        f32x4 zacc = (f32x4){0.f, 0.f, 0.f, 0.f};
#pragma unroll
        for (int ks = 0; ks < 16; ks++) {
          bf16x8 azf = *(const bf16x8*)((char*)lhb + SWZ2(c, ks * 64 + q * 16));
          bf16x8 bzf = *(const bf16x8*)((char*)lw_z + SWZ2(w * 16 + c, ks * 64 + q * 16));
          zacc = __builtin_amdgcn_mfma_f32_16x16x32_bf16(azf, bzf, zacc, 0, 0, 0);
        }
#pragma unroll
        for (int i = 0; i < 4; i++) {
          int row = q * 4 + i, zl = w * 16 + c;
          float gz = bf2f(*(const unsigned short*)((char*)lgz + row * 72 + zl * 2));
          float pre = zacc[i] + gz;
          pre = fminf(fmaxf(pre, -30.f), 30.f);
          lz[row * 32 + zl] = 1.f / (1.f + __expf(-pre));
        }
      }

#pragma unroll
      for (int ct = 0; ct < 8; ct++) {
        int j = rj0 + ct * 16 + c;
#pragma unroll
        for (int i = 0; i < 4; i++) {
          int row = q * 4 + i;
          float gr = bf2f(*(const unsigned short*)((char*)lgr + row * 1024 +
                           (((unsigned)(j * 2)) ^ LGRX(row))));
          float pre = racc[ct][i] * inv256 + gr;
          pre = fminf(fmaxf(pre, -30.f), 30.f);
          float r = 1.f / (1.f + __expf(-pre));
          float hb = bf2f(*(const unsigned short*)((char*)lhb + SWZ2(row, j * 2)));
          *(unsigned short*)((char*)lrh + SWZ2(row, j * 2)) = f2bf(r * hb);
        }
      }
      WAIT_LGKM0();
      SBAR();   // B3

      float hn[4];
      if (w >= 2) {
        f32x4 hacc = (f32x4){0.f, 0.f, 0.f, 0.f};
#pragma unroll
        for (int ks = 0; ks < 16; ks++) {
          bf16x8 arf = *(const bf16x8*)((char*)lrh + SWZ2(c, ks * 64 + q * 16));
          bf16x8 bhf = *(const bf16x8*)((char*)lw_h + SWZ2(hsub * 16 + c, ks * 64 + q * 16));
          hacc = __builtin_amdgcn_mfma_f32_16x16x32_bf16(arf, bhf, hacc, 0, 0, 0);
        }
#pragma unroll
        for (int i = 0; i < 4; i++) {
          int row = q * 4 + i, hl = hsub * 16 + c;
          float gh = bf2f(*(const unsigned short*)((char*)lgh + row * 72 + hl * 2));
          float pre = hacc[i] + gh;
          pre = fminf(fmaxf(pre, -15.f), 15.f);
          float e2 = __expf(2.f * pre);
          float th = (e2 - 1.f) / (e2 + 1.f);
          float z = lz[row * 32 + hl];
          hn[i] = hp[i] + z * (th - hp[i]);
          hp[i] = hn[i];
        }
#pragma unroll
        for (int i = 0; i < 4; i++) {
          float oth = __shfl_xor(hn[i], 1);
          if (!(c & 1)) {
            int b = bg * 16 + q * 4 + i;
            unsigned int pk = (unsigned int)f2bf(hn[i]) | ((unsigned int)f2bf(oth) << 16);
            __hip_atomic_store(
                (unsigned int*)&Hstb_w[(size_t)(dir * 64 + b) * 512 + j0 + hsub * 16 + c],
                pk, __ATOMIC_RELAXED, __HIP_MEMORY_SCOPE_AGENT);
          }
        }
        WAIT_VM0();
      }
      WAIT_LGKM0();
      SBAR();   // B4
      if (tid == 0)
        __hip_atomic_store(fown, (unsigned)(s + 1), __ATOMIC_RELAXED, __HIP_MEMORY_SCOPE_AGENT);
      if (w >= 2) {
        float* op = dir ? Hb : outp;
#pragma unroll
        for (int i = 0; i < 4; i++) {
          int b = bg * 16 + q * 4 + i;
          op[((size_t)b * TDIM + t) * HDIM + j0 + hsub * 16 + c] = hn[i];
        }
      }
    } else {
      // MODE 2: sync skeleton only
      SBAR();
      if (tid == 0)
        __hip_atomic_store(fown, (unsigned)(s + 1), __ATOMIC_RELAXED, __HIP_MEMORY_SCOPE_AGENT);
    }
  }
}

// ---------------- host ----------------

extern "C" void kernel_launch(void* const* d_in, const int* in_sizes, int n_in,
                              void* d_out, int out_size, void* d_ws, size_t ws_size,
                              hipStream_t stream) {
  (void)in_sizes; (void)n_in;
  const float* x  = (const float*)d_in[0];
  const float* h0 = (const float*)d_in[1];
  const float* Wz = (const float*)d_in[2];
  const float* bz = (const float*)d_in[3];
  const float* Wr = (const float*)d_in[4];
  const float* br = (const float*)d_in[5];
  const float* Wh = (const float*)d_in[6];
  const float* bh = (const float*)d_in[7];
  float* outp = (float*)d_out;

  const size_t szG    = (size_t)32768 * 1536 * 2;
  const size_t szXb   = (size_t)BDIM * TDIM * EDIM * 2;
  const size_t szW    = (size_t)3 * 512 * 512 * 2;
  const size_t szWr8  = (size_t)512 * 512;
  const size_t szHb   = (size_t)BDIM * TDIM * HDIM * 4;
  const size_t szHstb = (size_t)2 * 2 * 64 * 512 * 2;
  const size_t szFl   = 32768;
  const size_t fixed  = szXb + 2 * szW + szWr8 + szHb + 3 * szHstb + 3 * szFl + 16384;

  if (ws_size < fixed + szG) {
    sentinel_kern<<<256, 256, 0, stream>>>(outp, out_size);
    return;
  }

  size_t off = 0;
  char* base = (char*)d_ws;
  auto alloc = [&](size_t sz) { char* p = base + off; off = (off + sz + 255) & ~(size_t)255; return p; };
  unsigned short* Gb    = (unsigned short*)alloc(szG);
  unsigned short* xb    = (unsigned short*)alloc(szXb);
  unsigned short* Wxb   = (unsigned short*)alloc(szW);
  unsigned short* Whb   = (unsigned short*)alloc(szW);
  unsigned char*  Wr8   = (unsigned char*)alloc(szWr8);
  float*          Hbuf  = (float*)alloc(szHb);
  unsigned short* Hstb0 = (unsigned short*)alloc(szHstb);
  unsigned short* Hstb1 = (unsigned short*)alloc(szHstb);
  unsigned short* Hstb2 = (unsigned short*)alloc(szHstb);
  unsigned int*   fl0   = (unsigned int*)alloc(szFl);
  unsigned int*   fl1   = (unsigned int*)alloc(szFl);
  unsigned int*   fl2   = (unsigned int*)alloc(szFl);

  hipMemsetAsync(fl0, 0, szFl, stream);
  hipMemsetAsync(fl1, 0, szFl, stream);
  hipMemsetAsync(fl2, 0, szFl, stream);
  conv_w<<<(3 * 512 * 1024 + 255) / 256, 256, 0, stream>>>(Wz, Wr, Wh, Wxb, Whb, Wr8);
  conv_x<<<2048, 256, 0, stream>>>(x, xb, (BDIM * TDIM * EDIM) / 4);
  gru_xproj<<<dim3(256, 12), 256, 0, stream>>>(xb, Wxb, bz, br, bh, Gb);

  // Ablation dispatches (outputs overwritten by the real run below):
  gru_persist<1><<<128, 256, 0, stream>>>(Gb, h0, Hstb1, fl1, outp, Hbuf, Whb, Wr8);
  gru_persist<2><<<128, 256, 0, stream>>>(Gb, h0, Hstb2, fl2, outp, Hbuf, Whb, Wr8);
  // Real run (correct output):
  gru_persist<0><<<128, 256, 0, stream>>>(Gb, h0, Hstb0, fl0, outp, Hbuf, Whb, Wr8);

  add_out<<<2048, 256, 0, stream>>>(outp, Hbuf, (BDIM * TDIM * HDIM) / 4);
  hipMemcpyAsync(outp + (size_t)BDIM * TDIM * HDIM, h0,
                 (size_t)BDIM * HDIM * sizeof(float), hipMemcpyDeviceToDevice, stream);
}

// Round 9
// 2946.223 us; speedup vs baseline: 4.5453x; 4.5453x over previous
//
#include <hip/hip_runtime.h>
#include <stdint.h>

#define BDIM 64
#define TDIM 512
#define EDIM 512
#define HDIM 512

typedef __attribute__((ext_vector_type(8))) short bf16x8;
typedef __attribute__((ext_vector_type(4))) float f32x4;
typedef __attribute__((ext_vector_type(4))) unsigned int u32x4;
typedef __attribute__((ext_vector_type(4))) unsigned short u16x4;
typedef unsigned long long u64t;

static __device__ __forceinline__ unsigned short f2bf(float f) {
  union { float f; uint32_t u; } c; c.f = f;
  uint32_t u = c.u;
  uint32_t r = u + 0x7fffu + ((u >> 16) & 1u);
  return (unsigned short)(r >> 16);
}
static __device__ __forceinline__ float bf2f(unsigned short s) {
  union { uint32_t u; float f; } c; c.u = ((uint32_t)s) << 16;
  return c.f;
}

// swizzle for 1KB-row tiles (512 bf16 per row)
#define SWZ(row, byteInRow) ((((row)*1024) + (byteInRow)) ^ ((((row)&7))<<4))
// swizzle for 128B-row tiles (64 bf16 per row)
#define SWZA(row, byteInRow) ((((row)*128) + (byteInRow)) ^ ((((row)&7))<<4))

// ---------------- small utility kernels ----------------

__global__ void sentinel_kern(float* out, int n) {
  for (int i = blockIdx.x * blockDim.x + threadIdx.x; i < n; i += gridDim.x * blockDim.x)
    out[i] = -12345.0f;
}

__global__ void conv_w(const float* __restrict__ Wz, const float* __restrict__ Wr,
                       const float* __restrict__ Wh,
                       unsigned short* __restrict__ Wxb, unsigned short* __restrict__ Whb) {
  int idx = blockIdx.x * 256 + threadIdx.x;
  if (idx >= 3 * 512 * 1024) return;
  int g = idx >> 19;
  int rem = idx & 524287;
  int j = rem >> 10, k = rem & 1023;
  const float* W = (g == 0) ? Wz : (g == 1) ? Wr : Wh;
  unsigned short b = f2bf(W[(size_t)j * 1024 + k]);
  if (k < 512) Wxb[((size_t)g * 512 + j) * 512 + k] = b;
  else         Whb[((size_t)g * 512 + j) * 512 + (k - 512)] = b;
}

__global__ void conv_x(const float* __restrict__ x, unsigned short* __restrict__ xb, int n4) {
  for (int i = blockIdx.x * blockDim.x + threadIdx.x; i < n4; i += gridDim.x * blockDim.x) {
    f32x4 v = ((const f32x4*)x)[i];
    u16x4 o;
    o[0] = f2bf(v[0]); o[1] = f2bf(v[1]); o[2] = f2bf(v[2]); o[3] = f2bf(v[3]);
    ((u16x4*)xb)[i] = o;
  }
}

__global__ void add_out(float* __restrict__ out, const float* __restrict__ Hb, int n4) {
  for (int i = blockIdx.x * blockDim.x + threadIdx.x; i < n4; i += gridDim.x * blockDim.x) {
    f32x4 a = ((const f32x4*)out)[i];
    f32x4 b = ((const f32x4*)Hb)[i];
    ((f32x4*)out)[i] = a + b;
  }
}

// ---------------- phase A: G = x @ Wx^T + bias (bf16 out) ----------------

__global__ __launch_bounds__(256, 2)
void gru_xproj(const unsigned short* __restrict__ xb,
               const unsigned short* __restrict__ Wxb,
               const float* __restrict__ bz, const float* __restrict__ br,
               const float* __restrict__ bh,
               unsigned short* __restrict__ Gb) {
  __shared__ __align__(16) unsigned short lA[128 * 64];
  __shared__ __align__(16) unsigned short lB[128 * 64];
  const int tid = threadIdx.x;
  const int m0 = blockIdx.x * 128;
  const int n0 = blockIdx.y * 128;
  const int w = tid >> 6, lane = tid & 63, cl = lane & 15, q = lane >> 4;
  const int wr = w >> 1, wc = w & 1;
  f32x4 acc[4][4];
#pragma unroll
  for (int i = 0; i < 4; i++)
#pragma unroll
    for (int j = 0; j < 4; j++) acc[i][j] = (f32x4){0.f, 0.f, 0.f, 0.f};

  for (int ko = 0; ko < 8; ko++) {
    int k0 = ko * 64;
#pragma unroll
    for (int cc = 0; cc < 4; cc++) {
      int qq = tid * 4 + cc;
      int row = qq >> 3, kc = qq & 7;
      u32x4 va = *(const u32x4*)(xb + ((size_t)(m0 + row) * EDIM + k0 + kc * 8));
      *(u32x4*)((char*)lA + SWZA(row, kc * 16)) = va;
      u32x4 vb = *(const u32x4*)(Wxb + ((size_t)(n0 + row) * EDIM + k0 + kc * 8));
      *(u32x4*)((char*)lB + SWZA(row, kc * 16)) = vb;
    }
    __syncthreads();
#pragma unroll
    for (int ks = 0; ks < 2; ks++) {
      bf16x8 af[4], bfv[4];
#pragma unroll
      for (int i = 0; i < 4; i++) {
        int rl = wr * 64 + i * 16 + cl;
        af[i] = *(const bf16x8*)((char*)lA + SWZA(rl, ks * 64 + q * 16));
      }
#pragma unroll
      for (int j = 0; j < 4; j++) {
        int rl = wc * 64 + j * 16 + cl;
        bfv[j] = *(const bf16x8*)((char*)lB + SWZA(rl, ks * 64 + q * 16));
      }
#pragma unroll
      for (int i = 0; i < 4; i++)
#pragma unroll
        for (int j = 0; j < 4; j++)
          acc[i][j] = __builtin_amdgcn_mfma_f32_16x16x32_bf16(af[i], bfv[j], acc[i][j], 0, 0, 0);
    }
    __syncthreads();
  }
  const int g = n0 >> 9;
  const float* bias = (g == 0) ? bz : (g == 1) ? br : bh;
#pragma unroll
  for (int i = 0; i < 4; i++) {
#pragma unroll
    for (int j = 0; j < 4; j++) {
      int n = n0 + wc * 64 + j * 16 + cl;
      float bv = bias[n & 511];
#pragma unroll
      for (int ii = 0; ii < 4; ii++) {
        int m = m0 + wr * 64 + i * 16 + q * 4 + ii;
        Gb[(size_t)m * 1536 + n] = f2bf(acc[i][j][ii] + bv);
      }
    }
  }
}

// ---------------- persistent bidirectional recurrence (R2 + coalescing) -----
// 128 wgs: gid = bid&7 (dir = gid>>2, bg = gid&3); cg = bid>>3, cols j0=cg*32.
// Exchange: relaxed agent-scope atomics (proven). This round's only changes vs
// the proven R2 kernel: (1) staging loads coalesced (16 lanes = one contiguous
// 128B row segment), (2) publishes pair-packed to 4B stores.

__device__ __forceinline__ void gbar(unsigned int* ctr, unsigned int& ep, int tid) {
  asm volatile("s_waitcnt vmcnt(0)" ::: "memory");
  __syncthreads();
  if (tid == 0) {
    ep++;
    unsigned int target = ep * 16u;
    __hip_atomic_fetch_add(ctr, 1u, __ATOMIC_RELAXED, __HIP_MEMORY_SCOPE_AGENT);
    while (__hip_atomic_load(ctr, __ATOMIC_RELAXED, __HIP_MEMORY_SCOPE_AGENT) < target) {}
  }
  __syncthreads();
}

__global__ __launch_bounds__(256, 1)
void gru_persist(const unsigned short* __restrict__ Gb,
                 const float* __restrict__ h0,
                 unsigned short* __restrict__ Hst,    // [2*64][512] bf16
                 unsigned short* __restrict__ RHst,   // [2*64][512] bf16
                 unsigned int*   __restrict__ ctrs,   // 8 x 128B lines
                 float* __restrict__ outp,
                 float* __restrict__ Hb,
                 const unsigned short* __restrict__ Whb) {
  __shared__ __align__(16) unsigned short lds_w[6 * 16 * 512];   // 96KB
  __shared__ __align__(16) unsigned short lds_ah[16 * 512];      // 16KB
  __shared__ __align__(16) unsigned short lds_arh[16 * 512];     // 16KB
  __shared__ float lds_hprev[16 * 32];                            // 2KB

  const int tid = threadIdx.x;
  const int bid = blockIdx.x;
  const int gid = bid & 7;
  const int cg = bid >> 3;
  const int dir = gid >> 2;
  const int bg = gid & 3;
  const int j0 = cg * 32;
  const int w = tid >> 6;
  const int lane = tid & 63;
  const int c = lane & 15;
  const int q = lane >> 4;
  unsigned int* ctr = &ctrs[gid * 32];

  // ---- one-time: weight LDS tiles (nt = gate*2+sub) ----
  for (int qk = tid; qk < 6144; qk += 256) {
    int nt = qk >> 10;
    int cin = qk & 1023;
    int col = cin & 15;
    int kc = cin >> 4;
    int g = nt >> 1, sub2 = nt & 1;
    int jglob = j0 + sub2 * 16 + col;
    u32x4 v = *(const u32x4*)(Whb + (((size_t)g * 512 + jglob) * 512 + kc * 8));
    *(u32x4*)((char*)lds_w + nt * 16384 + SWZ(col, kc * 16)) = v;
  }

  // ---- init hprev (fp32, local cols) and Hst ----
#pragma unroll
  for (int ii = 0; ii < 2; ii++) {
    int idx = tid * 2 + ii;
    int row = idx >> 5, jl = idx & 31;
    int b = bg * 16 + row, j = j0 + jl;
    float v = h0[(size_t)b * HDIM + j];
    lds_hprev[row * 32 + jl] = v;
    __hip_atomic_store(&Hst[((size_t)dir * 64 + b) * 512 + j], f2bf(v),
                       __ATOMIC_RELAXED, __HIP_MEMORY_SCOPE_AGENT);
  }

  unsigned int ep = 0;
  gbar(ctr, ep, tid);

  const int sub = w & 1;
  const int jn = j0 + sub * 16 + c;
  const int gateA = (w < 2) ? 0 : 1;

  for (int s = 0; s < TDIM; s++) {
    int t = dir ? (TDIM - 1 - s) : s;

    // ---- prefetch G values for this step (plain cached loads) ----
    f32x4 gA, gC;
#pragma unroll
    for (int i = 0; i < 4; i++) {
      int b = bg * 16 + q * 4 + i;
      size_t mrow = (size_t)b * TDIM + t;
      size_t giA = (mrow * 3 + gateA) * HDIM + jn;
      gA[i] = bf2f(Gb[giA]);
      if (w < 2) {
        size_t giC = (mrow * 3 + 2) * HDIM + jn;
        gC[i] = bf2f(Gb[giC]);
      }
    }

    // ---- stage A_h: COALESCED atomic loads (16 lanes = 128B contiguous) ----
    {
      int row = tid >> 4, seg = tid & 15;
      const char* srcb = (const char*)Hst +
                         (size_t)(dir * 64 + bg * 16 + row) * 1024 + seg * 8;
      u64t v[8];
#pragma unroll
      for (int i = 0; i < 8; i++)
        v[i] = __hip_atomic_load((const u64t*)(srcb + i * 128),
                                 __ATOMIC_RELAXED, __HIP_MEMORY_SCOPE_AGENT);
      char* dst = (char*)lds_ah;
#pragma unroll
      for (int i = 0; i < 8; i++)
        *(u64t*)(dst + SWZ(row, seg * 8 + i * 128)) = v[i];
    }
    __syncthreads();

    // ---- P1: wave w computes tile nt=w (z: 0,1 ; r: 2,3), K=512 ----
    f32x4 a0 = (f32x4){0.f,0.f,0.f,0.f}, a1 = (f32x4){0.f,0.f,0.f,0.f};
    f32x4 a2 = (f32x4){0.f,0.f,0.f,0.f}, a3 = (f32x4){0.f,0.f,0.f,0.f};
    {
      const char* wb = (const char*)lds_w + w * 16384;
      const char* ab = (const char*)lds_ah;
#pragma unroll
      for (int ks = 0; ks < 4; ks++) {
#pragma unroll
        for (int p = 0; p < 4; p++) {
          int kb = (ks * 4 + p) * 64 + q * 16;
          bf16x8 af = *(const bf16x8*)(ab + SWZ(c, kb));
          bf16x8 bfv = *(const bf16x8*)(wb + SWZ(c, kb));
          if (p == 0) a0 = __builtin_amdgcn_mfma_f32_16x16x32_bf16(af, bfv, a0, 0, 0, 0);
          else if (p == 1) a1 = __builtin_amdgcn_mfma_f32_16x16x32_bf16(af, bfv, a1, 0, 0, 0);
          else if (p == 2) a2 = __builtin_amdgcn_mfma_f32_16x16x32_bf16(af, bfv, a2, 0, 0, 0);
          else a3 = __builtin_amdgcn_mfma_f32_16x16x32_bf16(af, bfv, a3, 0, 0, 0);
        }
      }
    }
    f32x4 acc = (a0 + a1) + (a2 + a3);
    f32x4 zreg;
    if (w < 2) {
#pragma unroll
      for (int i = 0; i < 4; i++) {
        float pre = acc[i] + gA[i];
        pre = fminf(fmaxf(pre, -30.f), 30.f);
        zreg[i] = 1.f / (1.f + __expf(-pre));
      }
    } else {
      // r pointwise + PACKED publish of r*h (4B stores by even-c lanes)
      float rhv[4];
#pragma unroll
      for (int i = 0; i < 4; i++) {
        int row = q * 4 + i;
        float pre = acc[i] + gA[i];
        pre = fminf(fmaxf(pre, -30.f), 30.f);
        float sg = 1.f / (1.f + __expf(-pre));
        rhv[i] = sg * lds_hprev[row * 32 + sub * 16 + c];
      }
#pragma unroll
      for (int i = 0; i < 4; i++) {
        float oth = __shfl_xor(rhv[i], 1);
        if (!(c & 1)) {
          int b = bg * 16 + q * 4 + i;
          unsigned int pk = (unsigned int)f2bf(rhv[i]) | ((unsigned int)f2bf(oth) << 16);
          __hip_atomic_store(
              (unsigned int*)&RHst[(size_t)(dir * 64 + b) * 512 + jn],
              pk, __ATOMIC_RELAXED, __HIP_MEMORY_SCOPE_AGENT);
        }
      }
    }
    gbar(ctr, ep, tid);   // barrier 1: r*h exchange complete

    // ---- stage A_rh: COALESCED atomic loads ----
    {
      int row = tid >> 4, seg = tid & 15;
      const char* srcb = (const char*)RHst +
                         (size_t)(dir * 64 + bg * 16 + row) * 1024 + seg * 8;
      u64t v[8];
#pragma unroll
      for (int i = 0; i < 8; i++)
        v[i] = __hip_atomic_load((const u64t*)(srcb + i * 128),
                                 __ATOMIC_RELAXED, __HIP_MEMORY_SCOPE_AGENT);
      char* dst = (char*)lds_arh;
#pragma unroll
      for (int i = 0; i < 8; i++)
        *(u64t*)(dst + SWZ(row, seg * 8 + i * 128)) = v[i];
    }
    __syncthreads();

    // ---- P2: waves 0,1 compute h~ tiles (nt = 4+sub), blend, publish ----
    if (w < 2) {
      f32x4 b0 = (f32x4){0.f,0.f,0.f,0.f}, b1 = (f32x4){0.f,0.f,0.f,0.f};
      f32x4 b2 = (f32x4){0.f,0.f,0.f,0.f}, b3 = (f32x4){0.f,0.f,0.f,0.f};
      const char* wb = (const char*)lds_w + (4 + sub) * 16384;
      const char* ab = (const char*)lds_arh;
#pragma unroll
      for (int ks = 0; ks < 4; ks++) {
#pragma unroll
        for (int p = 0; p < 4; p++) {
          int kb = (ks * 4 + p) * 64 + q * 16;
          bf16x8 af = *(const bf16x8*)(ab + SWZ(c, kb));
          bf16x8 bfv = *(const bf16x8*)(wb + SWZ(c, kb));
          if (p == 0) b0 = __builtin_amdgcn_mfma_f32_16x16x32_bf16(af, bfv, b0, 0, 0, 0);
          else if (p == 1) b1 = __builtin_amdgcn_mfma_f32_16x16x32_bf16(af, bfv, b1, 0, 0, 0);
          else if (p == 2) b2 = __builtin_amdgcn_mfma_f32_16x16x32_bf16(af, bfv, b2, 0, 0, 0);
          else b3 = __builtin_amdgcn_mfma_f32_16x16x32_bf16(af, bfv, b3, 0, 0, 0);
        }
      }
      f32x4 acc2 = (b0 + b1) + (b2 + b3);
      float* op = dir ? Hb : outp;
      float hn[4];
#pragma unroll
      for (int i = 0; i < 4; i++) {
        int row = q * 4 + i;
        int b = bg * 16 + row;
        float pre = acc2[i] + gC[i];
        pre = fminf(fmaxf(pre, -15.f), 15.f);
        float e2 = __expf(2.f * pre);
        float th = (e2 - 1.f) / (e2 + 1.f);
        float hp = lds_hprev[row * 32 + sub * 16 + c];
        float z = zreg[i];
        hn[i] = hp + z * (th - hp);
        op[((size_t)b * TDIM + t) * HDIM + jn] = hn[i];
        lds_hprev[row * 32 + sub * 16 + c] = hn[i];
      }
      // PACKED publish of h(t)
#pragma unroll
      for (int i = 0; i < 4; i++) {
        float oth = __shfl_xor(hn[i], 1);
        if (!(c & 1)) {
          int b = bg * 16 + q * 4 + i;
          unsigned int pk = (unsigned int)f2bf(hn[i]) | ((unsigned int)f2bf(oth) << 16);
          __hip_atomic_store(
              (unsigned int*)&Hst[(size_t)(dir * 64 + b) * 512 + jn],
              pk, __ATOMIC_RELAXED, __HIP_MEMORY_SCOPE_AGENT);
        }
      }
    }
    gbar(ctr, ep, tid);   // barrier 2: h(t) published
  }
}

// ---------------- host ----------------

extern "C" void kernel_launch(void* const* d_in, const int* in_sizes, int n_in,
                              void* d_out, int out_size, void* d_ws, size_t ws_size,
                              hipStream_t stream) {
  (void)in_sizes; (void)n_in;
  const float* x  = (const float*)d_in[0];
  const float* h0 = (const float*)d_in[1];
  const float* Wz = (const float*)d_in[2];
  const float* bz = (const float*)d_in[3];
  const float* Wr = (const float*)d_in[4];
  const float* br = (const float*)d_in[5];
  const float* Wh = (const float*)d_in[6];
  const float* bh = (const float*)d_in[7];
  float* outp = (float*)d_out;

  const size_t szG    = (size_t)32768 * 1536 * 2;       // bf16 G
  const size_t szXb   = (size_t)BDIM * TDIM * EDIM * 2;
  const size_t szW    = (size_t)3 * 512 * 512 * 2;
  const size_t szHb   = (size_t)BDIM * TDIM * HDIM * 4;
  const size_t szHst  = (size_t)2 * 64 * 512 * 2;
  const size_t szFl   = 4096;
  const size_t fixed  = szXb + 2 * szW + szHb + 2 * szHst + szFl + 16384;

  if (ws_size < fixed + szG) {
    sentinel_kern<<<256, 256, 0, stream>>>(outp, out_size);
    return;
  }

  size_t off = 0;
  char* base = (char*)d_ws;
  auto alloc = [&](size_t sz) { char* p = base + off; off = (off + sz + 255) & ~(size_t)255; return p; };
  unsigned short* Gb   = (unsigned short*)alloc(szG);
  unsigned short* xb   = (unsigned short*)alloc(szXb);
  unsigned short* Wxb  = (unsigned short*)alloc(szW);
  unsigned short* Whb  = (unsigned short*)alloc(szW);
  float*          Hbuf = (float*)alloc(szHb);
  unsigned short* Hst  = (unsigned short*)alloc(szHst);
  unsigned short* RHst = (unsigned short*)alloc(szHst);
  unsigned int*   ctrs = (unsigned int*)alloc(szFl);

  hipMemsetAsync(ctrs, 0, szFl, stream);
  conv_w<<<(3 * 512 * 1024 + 255) / 256, 256, 0, stream>>>(Wz, Wr, Wh, Wxb, Whb);
  conv_x<<<2048, 256, 0, stream>>>(x, xb, (BDIM * TDIM * EDIM) / 4);
  gru_xproj<<<dim3(256, 12), 256, 0, stream>>>(xb, Wxb, bz, br, bh, Gb);
  gru_persist<<<128, 256, 0, stream>>>(Gb, h0, Hst, RHst, ctrs, outp, Hbuf, Whb);
  add_out<<<2048, 256, 0, stream>>>(outp, Hbuf, (BDIM * TDIM * HDIM) / 4);
  hipMemcpyAsync(outp + (size_t)BDIM * TDIM * HDIM, h0,
                 (size_t)BDIM * HDIM * sizeof(float), hipMemcpyDeviceToDevice, stream);
}